// Round 1
// baseline (4311.560 us; speedup 1.0000x reference)
//
#include <hip/hip_runtime.h>

#define N_NODES 50000
#define N_EDGES 800000

// ---------------------------------------------------------------------------
// Edge-index dtype detection: reference says int64, but JAX default (x64 off)
// demotes to int32. If the buffer is int64 (little-endian, values < 2^31),
// every odd 32-bit word is 0. Random int32 indices in [0,50000) make that
// astronomically unlikely. flag = element stride in int32 units (1 or 2).
// ---------------------------------------------------------------------------
__global__ __launch_bounds__(1024) void detect_stride_k(const int* __restrict__ raw,
                                                        int* __restrict__ flag) {
    __shared__ int any_nonzero;
    if (threadIdx.x == 0) any_nonzero = 0;
    __syncthreads();
    int v = raw[2 * threadIdx.x + 1];   // odd positions 1..2047 (safe: >=1.6M ints)
    if (v != 0) atomicOr(&any_nonzero, 1);
    __syncthreads();
    if (threadIdx.x == 0) *flag = any_nonzero ? 1 : 2;
}

__global__ __launch_bounds__(256) void convert_edges_k(const int* __restrict__ raw,
        const int* __restrict__ flag, int* __restrict__ src, int* __restrict__ dst, int E) {
    int e = blockIdx.x * 256 + threadIdx.x;
    int stride = *flag;   // scalar-cached broadcast
    if (e < E) {
        src[e] = raw[(long long)e * stride];
        dst[e] = raw[((long long)E + e) * stride];
    }
}

__global__ __launch_bounds__(256) void deg_count_k(const int* __restrict__ dst,
                                                   float* deg, int E) {
    int e = blockIdx.x * 256 + threadIdx.x;
    if (e < E) unsafeAtomicAdd(&deg[dst[e]], 1.0f);   // exact: counts << 2^24
}

__global__ __launch_bounds__(256) void finish_dinv_k(float* deg, int n) {
    int i = blockIdx.x * 256 + threadIdx.x;
    if (i < n) deg[i] = rsqrtf(deg[i] + 1.0f);        // +1 self-loop
}

// ---------------------------------------------------------------------------
// H = X @ W.  K*M == 8192 for both layers -> Wl is exactly 32 KB LDS.
// 50000 % RPB(16) == 0, so no row-bounds checks needed.
// Each thread owns 4 consecutive output cols: 1 ds_read_b128 per 4 FMA.
// ---------------------------------------------------------------------------
template<int K, int M, int RPB>
__global__ __launch_bounds__(256) void gemm_xw_k(const float* __restrict__ X,
        const float* __restrict__ W, float* __restrict__ H) {
    __shared__ float Wl[K * M];
    __shared__ float Xl[RPB * K];
    for (int i = threadIdx.x * 4; i < K * M; i += 256 * 4)
        *(float4*)&Wl[i] = *(const float4*)&W[i];
    const int row0 = blockIdx.x * RPB;
    for (int i = threadIdx.x * 4; i < RPB * K; i += 256 * 4)
        *(float4*)&Xl[i] = *(const float4*)&X[(long long)row0 * K + i];
    __syncthreads();
    constexpr int CG = M / 4;               // col-groups of 4
    const int cg = threadIdx.x % CG;
    for (int r = threadIdx.x / CG; r < RPB; r += 256 / CG) {
        float4 acc = {0.f, 0.f, 0.f, 0.f};
        #pragma unroll
        for (int k = 0; k < K; k++) {
            float xv = Xl[r * K + k];                       // broadcast
            float4 wv = *(const float4*)&Wl[k * M + cg * 4];
            acc.x = fmaf(xv, wv.x, acc.x);
            acc.y = fmaf(xv, wv.y, acc.y);
            acc.z = fmaf(xv, wv.z, acc.z);
            acc.w = fmaf(xv, wv.w, acc.w);
        }
        *(float4*)&H[(long long)(row0 + r) * M + cg * 4] = acc;
    }
}

// ---------------------------------------------------------------------------
// agg[dst] += coef * h[src], coef = dinv[src]*dinv[dst].
// One thread per (edge, float4-chunk); consecutive threads cover one edge's
// feature row -> coalesced gather + coalesced (distinct-address) atomics.
// ---------------------------------------------------------------------------
template<int F>
__global__ __launch_bounds__(256) void edge_agg_k(const float* __restrict__ h,
        const int* __restrict__ src, const int* __restrict__ dst,
        const float* __restrict__ dinv, float* agg, int E) {
    constexpr int C = F / 4;
    int idx = blockIdx.x * 256 + threadIdx.x;
    if (idx >= E * C) return;
    int e = idx / C, c = idx % C;
    int s = src[e], d = dst[e];
    float coef = dinv[s] * dinv[d];
    float4 hv = *(const float4*)(h + (long long)s * F + c * 4);
    float* o = agg + (long long)d * F + c * 4;
    unsafeAtomicAdd(o + 0, hv.x * coef);
    unsafeAtomicAdd(o + 1, hv.y * coef);
    unsafeAtomicAdd(o + 2, hv.z * coef);
    unsafeAtomicAdd(o + 3, hv.w * coef);
}

// out = relu(agg + dinv^2 * h + b)   (out may alias agg: same-thread RMW only)
template<int F>
__global__ __launch_bounds__(256) void epilogue_k(const float* agg, const float* __restrict__ h,
        const float* __restrict__ dinv, const float* __restrict__ b, float* out, int n) {
    constexpr int C = F / 4;
    int idx = blockIdx.x * 256 + threadIdx.x;
    if (idx >= n * C) return;
    int i = idx / C, c = idx % C;
    float di = dinv[i], s2 = di * di;
    float4 a  = ((const float4*)agg)[idx];
    float4 hv = ((const float4*)h)[idx];
    float4 bv = *(const float4*)(b + c * 4);
    float4 o;
    o.x = fmaxf(fmaf(s2, hv.x, a.x) + bv.x, 0.f);
    o.y = fmaxf(fmaf(s2, hv.y, a.y) + bv.y, 0.f);
    o.z = fmaxf(fmaf(s2, hv.z, a.z) + bv.z, 0.f);
    o.w = fmaxf(fmaf(s2, hv.w, a.w) + bv.w, 0.f);
    ((float4*)out)[idx] = o;
}

extern "C" void kernel_launch(void* const* d_in, const int* in_sizes, int n_in,
                              void* d_out, int out_size, void* d_ws, size_t ws_size,
                              hipStream_t stream) {
    const float* x1 = (const float*)d_in[0];
    const int*   e1 = (const int*)d_in[1];
    const float* x2 = (const float*)d_in[2];
    const int*   e2 = (const int*)d_in[3];
    const float* W1 = (const float*)d_in[4];
    const float* b1 = (const float*)d_in[5];
    const float* W2 = (const float*)d_in[6];
    const float* b2 = (const float*)d_in[7];
    float* out = (float*)d_out;

    const int N = N_NODES, E = N_EDGES;

    // Workspace layout (~64.5 MB): flag | src1 dst1 src2 dst2 | dinv1 dinv2 | bufH | bufA
    char* ws = (char*)d_ws;
    int* flag  = (int*)ws;
    int* src1  = (int*)(ws + 256);
    int* dst1  = src1 + E;
    int* src2  = dst1 + E;
    int* dst2  = src2 + E;
    float* dinv1 = (float*)(dst2 + E);
    float* dinv2 = dinv1 + N;
    float* bufH  = dinv2 + N;               // N*128 floats
    float* bufA  = bufH + (size_t)N * 128;  // N*128 floats

    detect_stride_k<<<1, 1024, 0, stream>>>(e1, flag);
    convert_edges_k<<<(E + 255) / 256, 256, 0, stream>>>(e1, flag, src1, dst1, E);
    convert_edges_k<<<(E + 255) / 256, 256, 0, stream>>>(e2, flag, src2, dst2, E);

    // Degrees -> dinv (same for both layers; dinv1/dinv2 are contiguous)
    hipMemsetAsync(dinv1, 0, 2 * (size_t)N * sizeof(float), stream);
    deg_count_k<<<(E + 255) / 256, 256, 0, stream>>>(dst1, dinv1, E);
    deg_count_k<<<(E + 255) / 256, 256, 0, stream>>>(dst2, dinv2, E);
    finish_dinv_k<<<(2 * N + 255) / 256, 256, 0, stream>>>(dinv1, 2 * N);

    struct GraphCtx { const float* x; const int* src; const int* dst; const float* dinv; float* outp; };
    GraphCtx G[2] = {
        {x1, src1, dst1, dinv1, out},
        {x2, src2, dst2, dinv2, out + (size_t)N * 64},
    };

    for (int g = 0; g < 2; g++) {
        // ---- layer 1: 64 -> 128 ----
        gemm_xw_k<64, 128, 16><<<N / 16, 256, 0, stream>>>(G[g].x, W1, bufH);
        hipMemsetAsync(bufA, 0, (size_t)N * 128 * sizeof(float), stream);
        edge_agg_k<128><<<(E * 32 + 255) / 256, 256, 0, stream>>>(bufH, G[g].src, G[g].dst, G[g].dinv, bufA, E);
        epilogue_k<128><<<(N * 32 + 255) / 256, 256, 0, stream>>>(bufA, bufH, G[g].dinv, b1, bufA, N);
        // ---- layer 2: 128 -> 64 ----
        gemm_xw_k<128, 64, 16><<<N / 16, 256, 0, stream>>>(bufA, W2, bufH);
        hipMemsetAsync(bufA, 0, (size_t)N * 64 * sizeof(float), stream);
        edge_agg_k<64><<<(E * 16 + 255) / 256, 256, 0, stream>>>(bufH, G[g].src, G[g].dst, G[g].dinv, bufA, E);
        epilogue_k<64><<<(N * 16 + 255) / 256, 256, 0, stream>>>(bufA, bufH, G[g].dinv, b2, G[g].outp, N);
    }
}

// Round 2
// 630.031 us; speedup vs baseline: 6.8434x; 6.8434x over previous
//
#include <hip/hip_runtime.h>

#define N_NODES 50000
#define N_EDGES 800000

// ---------------------------------------------------------------------------
// Edge-index dtype detection: reference says int64, but JAX (x64 off) demotes
// to int32. If int64 little-endian with values < 2^31, every odd 32-bit word
// is 0. flag = element stride in int32 units (1 or 2).
// ---------------------------------------------------------------------------
__global__ __launch_bounds__(1024) void detect_stride_k(const int* __restrict__ raw,
                                                        int* __restrict__ flag) {
    __shared__ int any_nonzero;
    if (threadIdx.x == 0) any_nonzero = 0;
    __syncthreads();
    int v = raw[2 * threadIdx.x + 1];
    if (v != 0) atomicOr(&any_nonzero, 1);
    __syncthreads();
    if (threadIdx.x == 0) *flag = any_nonzero ? 1 : 2;
}

// Integer degree histogram over dst (reading raw edge_index with stride).
__global__ __launch_bounds__(256) void deg_count_k(const int* __restrict__ raw,
        const int* __restrict__ flag, int* __restrict__ deg, int E) {
    int e = blockIdx.x * 256 + threadIdx.x;
    int stride = *flag;
    if (e < E) atomicAdd(&deg[raw[((long long)E + e) * stride]], 1);
}

__global__ __launch_bounds__(256) void dinv_k(const int* __restrict__ deg,
                                              float* __restrict__ dinv, int n) {
    int i = blockIdx.x * 256 + threadIdx.x;
    if (i < n) dinv[i] = rsqrtf((float)deg[i] + 1.0f);   // +1 self-loop
}

// ---------------- 3-kernel exclusive scan (N=50000) ----------------
__global__ __launch_bounds__(256) void scan1_k(const int* __restrict__ deg,
        int* __restrict__ partial, int* __restrict__ blocksum, int n) {
    __shared__ int tmp[256];
    int t = threadIdx.x;
    int i = blockIdx.x * 256 + t;
    int v = (i < n) ? deg[i] : 0;
    tmp[t] = v;
    __syncthreads();
    #pragma unroll
    for (int off = 1; off < 256; off <<= 1) {
        int add = (t >= off) ? tmp[t - off] : 0;
        __syncthreads();
        tmp[t] += add;
        __syncthreads();
    }
    if (i < n) partial[i] = tmp[t] - v;          // exclusive
    if (t == 255) blocksum[blockIdx.x] = tmp[255];
}

__global__ __launch_bounds__(256) void scan2_k(int* __restrict__ blocksum, int nb) {
    __shared__ int tmp[256];
    int t = threadIdx.x;
    int v = (t < nb) ? blocksum[t] : 0;
    tmp[t] = v;
    __syncthreads();
    #pragma unroll
    for (int off = 1; off < 256; off <<= 1) {
        int add = (t >= off) ? tmp[t - off] : 0;
        __syncthreads();
        tmp[t] += add;
        __syncthreads();
    }
    if (t < nb) blocksum[t] = tmp[t] - v;        // exclusive block offsets
}

__global__ __launch_bounds__(256) void scan3_k(const int* __restrict__ partial,
        const int* __restrict__ blocksum, int* __restrict__ rowptr, int n, int total) {
    int i = blockIdx.x * 256 + threadIdx.x;
    if (i < n) rowptr[i] = partial[i] + blocksum[blockIdx.x];
    if (i == 0) rowptr[n] = total;
}

// Scatter edges into CSR buckets: csr[pos] = (src, bits(coef)).
__global__ __launch_bounds__(256) void scatter_k(const int* __restrict__ raw,
        const int* __restrict__ flag, const int* __restrict__ rowptr,
        int* __restrict__ cursor, const float* __restrict__ dinv,
        int2* __restrict__ csr, int E) {
    int e = blockIdx.x * 256 + threadIdx.x;
    if (e >= E) return;
    int stride = *flag;
    int s = raw[(long long)e * stride];
    int d = raw[((long long)E + e) * stride];
    int pos = rowptr[d] + atomicAdd(&cursor[d], 1);
    csr[pos] = make_int2(s, __float_as_int(dinv[s] * dinv[d]));
}

// ---------------------------------------------------------------------------
// Pull aggregation, F=64: one wave per node, lane = feature column.
// out[d] = sum_e coef_e * h[src_e] + dinv[d]^2 * h[d] (+bias, relu optional).
// Zero atomics; each output row written exactly once.
// ---------------------------------------------------------------------------
template<bool BIAS_RELU>
__global__ __launch_bounds__(256) void pull_agg_k(const float* __restrict__ h,
        const int2* __restrict__ csr, const int* __restrict__ rowptr,
        const float* __restrict__ dinv, const float* __restrict__ bias,
        float* __restrict__ out, int n) {
    const int lane = threadIdx.x & 63;
    const int d = blockIdx.x * 4 + (threadIdx.x >> 6);
    if (d >= n) return;
    int j = rowptr[d], end = rowptr[d + 1];
    float acc = 0.f;
    for (; j + 1 < end; j += 2) {           // unroll-2: two gathers in flight
        int2 p0 = csr[j], p1 = csr[j + 1];
        float v0 = h[(long long)p0.x * 64 + lane];
        float v1 = h[(long long)p1.x * 64 + lane];
        acc = fmaf(__int_as_float(p0.y), v0, acc);
        acc = fmaf(__int_as_float(p1.y), v1, acc);
    }
    if (j < end) {
        int2 p = csr[j];
        acc = fmaf(__int_as_float(p.y), h[(long long)p.x * 64 + lane], acc);
    }
    float di = dinv[d];
    acc = fmaf(di * di, h[(long long)d * 64 + lane], acc);
    if (BIAS_RELU) acc = fmaxf(acc + bias[lane], 0.f);
    out[(long long)d * 64 + lane] = acc;
}

// ---------------------------------------------------------------------------
// H = X @ W (+bias, relu optional). K*M == 8192 -> W is exactly 32 KB LDS.
// 50000 % RPB(16) == 0, no row-bounds checks.
// ---------------------------------------------------------------------------
template<int K, int M, int RPB, bool BIAS_RELU>
__global__ __launch_bounds__(256) void gemm_xw_k(const float* __restrict__ X,
        const float* __restrict__ W, const float* __restrict__ b,
        float* __restrict__ H) {
    __shared__ float Wl[K * M];
    __shared__ float Xl[RPB * K];
    for (int i = threadIdx.x * 4; i < K * M; i += 256 * 4)
        *(float4*)&Wl[i] = *(const float4*)&W[i];
    const int row0 = blockIdx.x * RPB;
    for (int i = threadIdx.x * 4; i < RPB * K; i += 256 * 4)
        *(float4*)&Xl[i] = *(const float4*)&X[(long long)row0 * K + i];
    __syncthreads();
    constexpr int CG = M / 4;
    const int cg = threadIdx.x % CG;
    for (int r = threadIdx.x / CG; r < RPB; r += 256 / CG) {
        float4 acc = {0.f, 0.f, 0.f, 0.f};
        #pragma unroll
        for (int k = 0; k < K; k++) {
            float xv = Xl[r * K + k];
            float4 wv = *(const float4*)&Wl[k * M + cg * 4];
            acc.x = fmaf(xv, wv.x, acc.x);
            acc.y = fmaf(xv, wv.y, acc.y);
            acc.z = fmaf(xv, wv.z, acc.z);
            acc.w = fmaf(xv, wv.w, acc.w);
        }
        if (BIAS_RELU) {
            float4 bv = *(const float4*)&b[cg * 4];
            acc.x = fmaxf(acc.x + bv.x, 0.f);
            acc.y = fmaxf(acc.y + bv.y, 0.f);
            acc.z = fmaxf(acc.z + bv.z, 0.f);
            acc.w = fmaxf(acc.w + bv.w, 0.f);
        }
        *(float4*)&H[(long long)(row0 + r) * M + cg * 4] = acc;
    }
}

extern "C" void kernel_launch(void* const* d_in, const int* in_sizes, int n_in,
                              void* d_out, int out_size, void* d_ws, size_t ws_size,
                              hipStream_t stream) {
    const float* x1 = (const float*)d_in[0];
    const int*   e1 = (const int*)d_in[1];
    const float* x2 = (const float*)d_in[2];
    const int*   e2 = (const int*)d_in[3];
    const float* W1 = (const float*)d_in[4];
    const float* b1 = (const float*)d_in[5];
    const float* W2 = (const float*)d_in[6];
    const float* b2 = (const float*)d_in[7];
    float* out = (float*)d_out;

    const int N = N_NODES, E = N_EDGES;
    const int NB = (N + 255) / 256;          // 196 scan blocks

    // Workspace (~46 MB): flag | deg,cursor (contig for 1 memset) | dinv |
    // rowptr | partial | blocksum | csr | bufY (also G) | bufH
    char* ws = (char*)d_ws;
    int*   flag     = (int*)ws;
    int*   deg      = (int*)(ws + 256);
    int*   cursor   = deg + N;
    float* dinv     = (float*)(cursor + N);
    int*   rowptr   = (int*)(dinv + N);
    int*   partial  = rowptr + (N + 1);
    int*   blocksum = partial + N;           // 256 ints
    int2*  csr      = (int2*)(((char*)(blocksum + 256)) );
    float* bufY     = (float*)(csr + E);               // N*64, also holds G
    float* bufH     = bufY + (size_t)N * 64;           // N*128

    detect_stride_k<<<1, 1024, 0, stream>>>(e1, flag);

    struct GraphCtx { const float* x; const int* raw; float* outp; };
    GraphCtx G[2] = { {x1, e1, out}, {x2, e2, out + (size_t)N * 64} };

    for (int g = 0; g < 2; g++) {
        const int* raw = G[g].raw;
        // ---- CSR build (shared by both layers of this graph) ----
        hipMemsetAsync(deg, 0, 2 * (size_t)N * sizeof(int), stream);  // deg+cursor
        deg_count_k<<<(E + 255) / 256, 256, 0, stream>>>(raw, flag, deg, E);
        dinv_k<<<(N + 255) / 256, 256, 0, stream>>>(deg, dinv, N);
        scan1_k<<<NB, 256, 0, stream>>>(deg, partial, blocksum, N);
        scan2_k<<<1, 256, 0, stream>>>(blocksum, NB);
        scan3_k<<<NB, 256, 0, stream>>>(partial, blocksum, rowptr, N, E);
        scatter_k<<<(E + 255) / 256, 256, 0, stream>>>(raw, flag, rowptr, cursor, dinv, csr, E);
        // ---- layer 1: Y = A_hat @ X (F=64), then X1 = relu(Y@W1 + b1) ----
        pull_agg_k<false><<<(N + 3) / 4, 256, 0, stream>>>(G[g].x, csr, rowptr, dinv, nullptr, bufY, N);
        gemm_xw_k<64, 128, 16, true><<<N / 16, 256, 0, stream>>>(bufY, W1, b1, bufH);
        // ---- layer 2: G = X1@W2, then out = relu(A_hat @ G + b2) ----
        gemm_xw_k<128, 64, 16, false><<<N / 16, 256, 0, stream>>>(bufH, W2, nullptr, bufY);
        pull_agg_k<true><<<(N + 3) / 4, 256, 0, stream>>>(bufY, csr, rowptr, dinv, b2, G[g].outp, N);
    }
}

// Round 3
// 468.680 us; speedup vs baseline: 9.1994x; 1.3443x over previous
//
#include <hip/hip_runtime.h>

#define N_NODES 50000
#define N_EDGES 800000
// Both graphs are processed in one concatenated space: nodes [0,2N), edges [0,2E).

// ---------------------------------------------------------------------------
// Edge-index dtype detection: reference says int64, but JAX (x64 off) demotes
// to int32. If int64 little-endian with values < 2^31, every odd 32-bit word
// is 0. flag = element stride in int32 units (1 or 2).
// ---------------------------------------------------------------------------
__global__ __launch_bounds__(1024) void detect_stride_k(const int* __restrict__ raw,
                                                        int* __restrict__ flag) {
    __shared__ int any_nonzero;
    if (threadIdx.x == 0) any_nonzero = 0;
    __syncthreads();
    int v = raw[2 * threadIdx.x + 1];
    if (v != 0) atomicOr(&any_nonzero, 1);
    __syncthreads();
    if (threadIdx.x == 0) *flag = any_nonzero ? 1 : 2;
}

// Degree histogram over dst, both graphs at once (node gid = g*N + dst).
__global__ __launch_bounds__(256) void deg_count_k(const int* __restrict__ raw1,
        const int* __restrict__ raw2, const int* __restrict__ flag,
        int* __restrict__ deg) {
    int e = blockIdx.x * 256 + threadIdx.x;
    if (e >= 2 * N_EDGES) return;
    int stride = *flag;
    const int* raw = (e < N_EDGES) ? raw1 : raw2;
    int gbase = (e < N_EDGES) ? 0 : N_NODES;
    int el = (e < N_EDGES) ? e : e - N_EDGES;
    int d = raw[((long long)N_EDGES + el) * stride];
    atomicAdd(&deg[gbase + d], 1);
}

// ---------------- exclusive scan over 2N, dinv fused into pass 1 ----------
__global__ __launch_bounds__(256) void scan1_k(const int* __restrict__ deg,
        float* __restrict__ dinv, int* __restrict__ partial,
        int* __restrict__ blocksum, int n) {
    __shared__ int tmp[256];
    int t = threadIdx.x;
    int i = blockIdx.x * 256 + t;
    int v = (i < n) ? deg[i] : 0;
    if (i < n) dinv[i] = rsqrtf((float)v + 1.0f);   // +1 self-loop
    tmp[t] = v;
    __syncthreads();
    #pragma unroll
    for (int off = 1; off < 256; off <<= 1) {
        int add = (t >= off) ? tmp[t - off] : 0;
        __syncthreads();
        tmp[t] += add;
        __syncthreads();
    }
    if (i < n) partial[i] = tmp[t] - v;             // exclusive
    if (t == 255) blocksum[blockIdx.x] = tmp[255];
}

__global__ __launch_bounds__(512) void scan2_k(int* __restrict__ blocksum, int nb) {
    __shared__ int tmp[512];
    int t = threadIdx.x;
    int v = (t < nb) ? blocksum[t] : 0;
    tmp[t] = v;
    __syncthreads();
    #pragma unroll
    for (int off = 1; off < 512; off <<= 1) {
        int add = (t >= off) ? tmp[t - off] : 0;
        __syncthreads();
        tmp[t] += add;
        __syncthreads();
    }
    if (t < nb) blocksum[t] = tmp[t] - v;           // exclusive block offsets
}

__global__ __launch_bounds__(256) void scan3_k(const int* __restrict__ partial,
        const int* __restrict__ blocksum, int* __restrict__ rowptr, int n, int total) {
    int i = blockIdx.x * 256 + threadIdx.x;
    if (i < n) rowptr[i] = partial[i] + blocksum[blockIdx.x];
    if (i == 0) rowptr[n] = total;
}

// Scatter edges into CSR buckets: csr[pos] = (src_local, bits(coef)).
__global__ __launch_bounds__(256) void scatter_k(const int* __restrict__ raw1,
        const int* __restrict__ raw2, const int* __restrict__ flag,
        const int* __restrict__ rowptr, int* __restrict__ cursor,
        const float* __restrict__ dinv, int2* __restrict__ csr) {
    int e = blockIdx.x * 256 + threadIdx.x;
    if (e >= 2 * N_EDGES) return;
    int stride = *flag;
    const int* raw = (e < N_EDGES) ? raw1 : raw2;
    int gbase = (e < N_EDGES) ? 0 : N_NODES;
    int el = (e < N_EDGES) ? e : e - N_EDGES;
    int s = raw[(long long)el * stride];
    int d = raw[((long long)N_EDGES + el) * stride];
    int gd = gbase + d;
    int pos = rowptr[gd] + atomicAdd(&cursor[gd], 1);
    csr[pos] = make_int2(s, __float_as_int(dinv[gbase + s] * dinv[gd]));
}

// ---------------------------------------------------------------------------
// Pull aggregation, F=64, both graphs: one wave per node, lane = feature.
// 8 gathers in flight per lane; csr/rowptr reads are wave-uniform (s_load).
// ---------------------------------------------------------------------------
template<bool BIAS_RELU>
__global__ __launch_bounds__(256) void pull_agg_k(const float* __restrict__ h1,
        const float* __restrict__ h2, const int2* __restrict__ csr,
        const int* __restrict__ rowptr, const float* __restrict__ dinv,
        const float* __restrict__ bias, float* __restrict__ out, int n2) {
    const int lane = threadIdx.x & 63;
    const int gid = blockIdx.x * 4 + (threadIdx.x >> 6);
    if (gid >= n2) return;
    const float* h = (gid < N_NODES) ? h1 : h2;
    const int local = (gid < N_NODES) ? gid : gid - N_NODES;
    int j = rowptr[gid], end = rowptr[gid + 1];
    float acc = 0.f;
    for (; j + 8 <= end; j += 8) {
        int2 p[8]; float v[8];
        #pragma unroll
        for (int u = 0; u < 8; u++) p[u] = csr[j + u];
        #pragma unroll
        for (int u = 0; u < 8; u++) v[u] = h[(size_t)p[u].x * 64 + lane];
        #pragma unroll
        for (int u = 0; u < 8; u++) acc = fmaf(__int_as_float(p[u].y), v[u], acc);
    }
    for (; j < end; j++) {
        int2 p = csr[j];
        acc = fmaf(__int_as_float(p.y), h[(size_t)p.x * 64 + lane], acc);
    }
    float di = dinv[gid];
    acc = fmaf(di * di, h[(size_t)local * 64 + lane], acc);
    if (BIAS_RELU) acc = fmaxf(acc + bias[lane], 0.f);
    out[(size_t)gid * 64 + lane] = acc;
}

// ---------------------------------------------------------------------------
// H = X @ W (+bias,relu). Per-thread 4 rows x 4 cols -> 16 FMA per k-iter
// against 1 ds_read_b128 (W) + 4 ds_read_b32 (X broadcast). Xl stride K+1:
// banks (4*rg+i)*(K+1) mod 32 distinct across rg -> conflict-free.
// RPB = 256/(M/4)*4: layer1 (M=128) 32 rows, layer2 (M=64) 64 rows.
// ---------------------------------------------------------------------------
template<int K, int M, int RPB, bool BIAS_RELU>
__global__ __launch_bounds__(256) void gemm_xw_k(const float* __restrict__ X,
        const float* __restrict__ W, const float* __restrict__ b,
        float* __restrict__ H, int nrows) {
    constexpr int XS = K + 1;
    __shared__ float Wl[K * M];        // 32 KB
    __shared__ float Xl[RPB * XS];
    const int tid = threadIdx.x;
    for (int i = tid * 4; i < K * M; i += 1024)
        *(float4*)&Wl[i] = *(const float4*)&W[i];
    const int row0 = blockIdx.x * RPB;
    for (int i = tid * 4; i < RPB * K; i += 1024) {
        int r = i / K, k = i % K;
        float4 v = make_float4(0.f, 0.f, 0.f, 0.f);
        if (row0 + r < nrows) v = *(const float4*)&X[(size_t)(row0 + r) * K + k];
        Xl[r * XS + k]     = v.x;
        Xl[r * XS + k + 1] = v.y;
        Xl[r * XS + k + 2] = v.z;
        Xl[r * XS + k + 3] = v.w;
    }
    __syncthreads();
    constexpr int CG = M / 4;
    const int cg = tid % CG;
    const int rg = tid / CG;           // rows rg*4 .. rg*4+3
    float4 acc[4] = {};
    #pragma unroll 4
    for (int k = 0; k < K; k++) {
        float4 w4 = *(const float4*)&Wl[k * M + cg * 4];
        #pragma unroll
        for (int i = 0; i < 4; i++) {
            float xv = Xl[(rg * 4 + i) * XS + k];
            acc[i].x = fmaf(xv, w4.x, acc[i].x);
            acc[i].y = fmaf(xv, w4.y, acc[i].y);
            acc[i].z = fmaf(xv, w4.z, acc[i].z);
            acc[i].w = fmaf(xv, w4.w, acc[i].w);
        }
    }
    float4 bv = make_float4(0.f, 0.f, 0.f, 0.f);
    if (BIAS_RELU) bv = *(const float4*)&b[cg * 4];
    #pragma unroll
    for (int i = 0; i < 4; i++) {
        int r = row0 + rg * 4 + i;
        if (r < nrows) {
            float4 o = acc[i];
            if (BIAS_RELU) {
                o.x = fmaxf(o.x + bv.x, 0.f);
                o.y = fmaxf(o.y + bv.y, 0.f);
                o.z = fmaxf(o.z + bv.z, 0.f);
                o.w = fmaxf(o.w + bv.w, 0.f);
            }
            *(float4*)&H[(size_t)r * M + cg * 4] = o;
        }
    }
}

extern "C" void kernel_launch(void* const* d_in, const int* in_sizes, int n_in,
                              void* d_out, int out_size, void* d_ws, size_t ws_size,
                              hipStream_t stream) {
    const float* x1 = (const float*)d_in[0];
    const int*   e1 = (const int*)d_in[1];
    const float* x2 = (const float*)d_in[2];
    const int*   e2 = (const int*)d_in[3];
    const float* W1 = (const float*)d_in[4];
    const float* b1 = (const float*)d_in[5];
    const float* W2 = (const float*)d_in[6];
    const float* b2 = (const float*)d_in[7];
    float* out = (float*)d_out;

    const int N2 = 2 * N_NODES, E2 = 2 * N_EDGES;
    const int NB = (N2 + 255) / 256;            // 391 scan blocks (<512)

    // Workspace (~91 MB): flag | deg,cursor | dinv | rowptr | partial |
    // blocksum | csr(2E int2) | bufY(2N*64) | bufH(2N*128)
    char* ws = (char*)d_ws;
    int*   flag     = (int*)ws;
    int*   deg      = (int*)(ws + 256);
    int*   cursor   = deg + N2;
    float* dinv     = (float*)(cursor + N2);
    int*   rowptr   = (int*)(dinv + N2);
    int*   partial  = rowptr + (N2 + 1);
    int*   blocksum = partial + N2;             // 512 ints
    int2*  csr      = (int2*)(blocksum + 512);
    float* bufY     = (float*)(csr + E2);       // 2N*64
    float* bufH     = bufY + (size_t)N2 * 64;   // 2N*128

    detect_stride_k<<<1, 1024, 0, stream>>>(e1, flag);

    // ---- CSR build, both graphs ----
    hipMemsetAsync(deg, 0, 2 * (size_t)N2 * sizeof(int), stream);   // deg+cursor
    deg_count_k<<<(E2 + 255) / 256, 256, 0, stream>>>(e1, e2, flag, deg);
    scan1_k<<<NB, 256, 0, stream>>>(deg, dinv, partial, blocksum, N2);
    scan2_k<<<1, 512, 0, stream>>>(blocksum, NB);
    scan3_k<<<NB, 256, 0, stream>>>(partial, blocksum, rowptr, N2, E2);
    scatter_k<<<(E2 + 255) / 256, 256, 0, stream>>>(e1, e2, flag, rowptr, cursor, dinv, csr);

    // ---- layer 1: Y = A_hat @ X (F=64), X1 = relu(Y@W1 + b1) ----
    pull_agg_k<false><<<(N2 + 3) / 4, 256, 0, stream>>>(x1, x2, csr, rowptr, dinv, nullptr, bufY, N2);
    gemm_xw_k<64, 128, 32, true><<<(N2 + 31) / 32, 256, 0, stream>>>(bufY, W1, b1, bufH, N2);
    // ---- layer 2: G = X1@W2, out = relu(A_hat @ G + b2) ----
    gemm_xw_k<128, 64, 64, false><<<(N2 + 63) / 64, 256, 0, stream>>>(bufH, W2, nullptr, bufY, N2);
    pull_agg_k<true><<<(N2 + 3) / 4, 256, 0, stream>>>(bufY, bufY + (size_t)N_NODES * 64,
                                                      csr, rowptr, dinv, b2, out, N2);
}

// Round 4
// 458.899 us; speedup vs baseline: 9.3954x; 1.0213x over previous
//
#include <hip/hip_runtime.h>

#define N_NODES 50000
#define N_EDGES 800000
static_assert(N_NODES < 65536, "u16 CSR requires local node ids < 65536");
// Both graphs live in one concatenated space: nodes [0,2N), edges [0,2E).

// ---------------------------------------------------------------------------
// Edge-index dtype detection: reference says int64, but JAX (x64 off) demotes
// to int32. If int64 little-endian with values < 2^31, every odd 32-bit word
// is 0. flag = element stride in int32 units (1 or 2).
// ---------------------------------------------------------------------------
__global__ __launch_bounds__(1024) void detect_stride_k(const int* __restrict__ raw,
                                                        int* __restrict__ flag) {
    __shared__ int any_nonzero;
    if (threadIdx.x == 0) any_nonzero = 0;
    __syncthreads();
    int v = raw[2 * threadIdx.x + 1];
    if (v != 0) atomicOr(&any_nonzero, 1);
    __syncthreads();
    if (threadIdx.x == 0) *flag = any_nonzero ? 1 : 2;
}

// Degree histogram over dst, both graphs at once (node gid = g*N + dst).
__global__ __launch_bounds__(256) void deg_count_k(const int* __restrict__ raw1,
        const int* __restrict__ raw2, const int* __restrict__ flag,
        int* __restrict__ deg) {
    int e = blockIdx.x * 256 + threadIdx.x;
    if (e >= 2 * N_EDGES) return;
    int stride = *flag;
    const int* raw = (e < N_EDGES) ? raw1 : raw2;
    int gbase = (e < N_EDGES) ? 0 : N_NODES;
    int el = (e < N_EDGES) ? e : e - N_EDGES;
    int d = raw[((long long)N_EDGES + el) * stride];
    atomicAdd(&deg[gbase + d], 1);
}

// ---------------- exclusive scan over 2N, dinv fused into pass 1 ----------
__global__ __launch_bounds__(256) void scan1_k(const int* __restrict__ deg,
        float* __restrict__ dinv, int* __restrict__ partial,
        int* __restrict__ blocksum, int n) {
    __shared__ int tmp[256];
    int t = threadIdx.x;
    int i = blockIdx.x * 256 + t;
    int v = (i < n) ? deg[i] : 0;
    if (i < n) dinv[i] = rsqrtf((float)v + 1.0f);   // +1 self-loop
    tmp[t] = v;
    __syncthreads();
    #pragma unroll
    for (int off = 1; off < 256; off <<= 1) {
        int add = (t >= off) ? tmp[t - off] : 0;
        __syncthreads();
        tmp[t] += add;
        __syncthreads();
    }
    if (i < n) partial[i] = tmp[t] - v;             // exclusive
    if (t == 255) blocksum[blockIdx.x] = tmp[255];
}

__global__ __launch_bounds__(512) void scan2_k(int* __restrict__ blocksum, int nb) {
    __shared__ int tmp[512];
    int t = threadIdx.x;
    int v = (t < nb) ? blocksum[t] : 0;
    tmp[t] = v;
    __syncthreads();
    #pragma unroll
    for (int off = 1; off < 512; off <<= 1) {
        int add = (t >= off) ? tmp[t - off] : 0;
        __syncthreads();
        tmp[t] += add;
        __syncthreads();
    }
    if (t < nb) blocksum[t] = tmp[t] - v;           // exclusive block offsets
}

__global__ __launch_bounds__(256) void scan3_k(const int* __restrict__ partial,
        const int* __restrict__ blocksum, int* __restrict__ rowptr, int n, int total) {
    int i = blockIdx.x * 256 + threadIdx.x;
    if (i < n) rowptr[i] = partial[i] + blocksum[blockIdx.x];
    if (i == 0) rowptr[n] = total;
}

// Scatter edges into CSR buckets: csr[pos] = local src (u16). Graph id is
// implied by dst at pull time. 2 B random writes vs 8 B: ~4x less writeback.
__global__ __launch_bounds__(256) void scatter_k(const int* __restrict__ raw1,
        const int* __restrict__ raw2, const int* __restrict__ flag,
        const int* __restrict__ rowptr, int* __restrict__ cursor,
        unsigned short* __restrict__ csr) {
    int e = blockIdx.x * 256 + threadIdx.x;
    if (e >= 2 * N_EDGES) return;
    int stride = *flag;
    const int* raw = (e < N_EDGES) ? raw1 : raw2;
    int gbase = (e < N_EDGES) ? 0 : N_NODES;
    int el = (e < N_EDGES) ? e : e - N_EDGES;
    int s = raw[(long long)el * stride];
    int d = raw[((long long)N_EDGES + el) * stride];
    int gd = gbase + d;
    int pos = rowptr[gd] + atomicAdd(&cursor[gd], 1);
    csr[pos] = (unsigned short)s;
}

// sx[gid] = dinv[gid] * x[gid]  (prescaled input features, both graphs)
__global__ __launch_bounds__(256) void prescale_k(const float* __restrict__ x1,
        const float* __restrict__ x2, const float* __restrict__ dinv,
        float* __restrict__ sx) {
    int idx = blockIdx.x * 256 + threadIdx.x;        // float4 index
    if (idx >= 2 * N_NODES * 16) return;
    int gid = idx >> 4;
    const float* x = (gid < N_NODES) ? x1 : x2;
    size_t off = (gid < N_NODES) ? (size_t)idx * 4 : ((size_t)idx - (size_t)N_NODES * 16) * 4;
    float4 v = *(const float4*)&x[off];
    float dv = dinv[gid];
    v.x *= dv; v.y *= dv; v.z *= dv; v.w *= dv;
    ((float4*)sx)[idx] = v;
}

// ---------------------------------------------------------------------------
// Pull aggregation on PRESCALED features, F=64: one wave per dst node.
// Lane = (sub, fl): 4 edges in parallel, 16 lanes x float4 per edge row.
// out[d] = dinv[d] * (sum_s sh[s] + sh[d]) (+bias, relu).
// Main loop: 16 edges / iter -> 16 float4 gathers (4 KB) in flight per wave.
// ---------------------------------------------------------------------------
template<bool BIAS_RELU>
__global__ __launch_bounds__(256) void pull_agg_k(const float* __restrict__ sh,
        const unsigned short* __restrict__ csr, const int* __restrict__ rowptr,
        const float* __restrict__ dinv, const float* __restrict__ bias,
        float* __restrict__ out, int n2) {
    const int lane = threadIdx.x & 63;
    const int d = blockIdx.x * 4 + (threadIdx.x >> 6);
    if (d >= n2) return;
    const int sub = lane >> 4, fl = lane & 15;
    const int gbase = (d < N_NODES) ? 0 : N_NODES;
    const int jb = rowptr[d], je = rowptr[d + 1];
    float4 acc = {0.f, 0.f, 0.f, 0.f};
    int j = jb;
    for (; j + 16 <= je; j += 16) {
        int s0 = (int)csr[j      + sub] + gbase;
        int s1 = (int)csr[j + 4  + sub] + gbase;
        int s2 = (int)csr[j + 8  + sub] + gbase;
        int s3 = (int)csr[j + 12 + sub] + gbase;
        float4 v0 = *(const float4*)&sh[(size_t)s0 * 64 + fl * 4];
        float4 v1 = *(const float4*)&sh[(size_t)s1 * 64 + fl * 4];
        float4 v2 = *(const float4*)&sh[(size_t)s2 * 64 + fl * 4];
        float4 v3 = *(const float4*)&sh[(size_t)s3 * 64 + fl * 4];
        acc.x += v0.x + v1.x + v2.x + v3.x;
        acc.y += v0.y + v1.y + v2.y + v3.y;
        acc.z += v0.z + v1.z + v2.z + v3.z;
        acc.w += v0.w + v1.w + v2.w + v3.w;
    }
    for (; j < je; j += 4) {
        int idx = j + sub;
        int ii = (idx < je) ? idx : jb;              // safe addr (row nonempty here)
        int s = (int)csr[ii] + gbase;
        float4 v = *(const float4*)&sh[(size_t)s * 64 + fl * 4];
        if (idx < je) { acc.x += v.x; acc.y += v.y; acc.z += v.z; acc.w += v.w; }
    }
    // reduce over the 4 subs (lanes fl, fl+16, fl+32, fl+48)
    acc.x += __shfl_xor(acc.x, 16); acc.y += __shfl_xor(acc.y, 16);
    acc.z += __shfl_xor(acc.z, 16); acc.w += __shfl_xor(acc.w, 16);
    acc.x += __shfl_xor(acc.x, 32); acc.y += __shfl_xor(acc.y, 32);
    acc.z += __shfl_xor(acc.z, 32); acc.w += __shfl_xor(acc.w, 32);
    float4 self4 = *(const float4*)&sh[(size_t)d * 64 + fl * 4];
    float dv = dinv[d];
    float4 o;
    o.x = (acc.x + self4.x) * dv;
    o.y = (acc.y + self4.y) * dv;
    o.z = (acc.z + self4.z) * dv;
    o.w = (acc.w + self4.w) * dv;
    if (BIAS_RELU) {
        float4 bv = *(const float4*)&bias[fl * 4];
        o.x = fmaxf(o.x + bv.x, 0.f);
        o.y = fmaxf(o.y + bv.y, 0.f);
        o.z = fmaxf(o.z + bv.z, 0.f);
        o.w = fmaxf(o.w + bv.w, 0.f);
    }
    if (sub == 0) *(float4*)&out[(size_t)d * 64 + fl * 4] = o;
}

// ---------------------------------------------------------------------------
// H = X @ W with fused epilogue. Per-thread 8 rows x 4 cols; X read as
// float4-over-k from XOR-swizzled LDS (<=2-way bank aliasing = free).
// Per k4-iter: 12 ds_read_b128 vs 128 FMA. K=128 runs in two 64-k halves
// re-staging a 32 KB Xl. EPI: 0 = bias+relu, 1 = scale row by dinv (prescale
// for the following pull).
// ---------------------------------------------------------------------------
template<int K, int M, int CG, int RPT, int KH, int EPI>
__global__ __launch_bounds__(256) void gemm_xw_k(const float* __restrict__ X,
        const float* __restrict__ W, const float* __restrict__ b,
        const float* __restrict__ dinv, float* __restrict__ H, int nrows) {
    constexpr int RT  = 256 / CG;        // row-thread groups
    constexpr int RPB = RT * RPT;        // rows per block
    constexpr int KHS = K / KH;          // k per half (64)
    constexpr int Q   = KHS / 4;         // float4s per row-half (16)
    __shared__ float Wl[K * M];          // 32 KB
    __shared__ float Xl[RPB * KHS];      // 16 KB (L1) / 32 KB (L2)
    const int tid = threadIdx.x;
    const int cg = tid % CG, rt = tid / CG;
    const int row0 = blockIdx.x * RPB;
    for (int i = tid * 4; i < K * M; i += 1024)
        *(float4*)&Wl[i] = *(const float4*)&W[i];
    float4 acc[RPT] = {};
    for (int h = 0; h < KH; h++) {
        __syncthreads();                 // protect Xl reuse across halves
        for (int i4 = tid; i4 < RPB * Q; i4 += 256) {
            int rr = i4 / Q, q = i4 % Q;
            int grow = row0 + rr;
            float4 v = {0.f, 0.f, 0.f, 0.f};
            if (grow < nrows) v = *(const float4*)&X[(size_t)grow * K + h * KHS + q * 4];
            ((float4*)Xl)[rr * Q + (q ^ (rr & (Q - 1)))] = v;
        }
        __syncthreads();
        for (int k4 = 0; k4 < Q; k4++) {
            float xr[RPT][4];
            #pragma unroll
            for (int i = 0; i < RPT; i++) {
                int rr = rt * RPT + i;
                float4 xv = ((const float4*)Xl)[rr * Q + (k4 ^ (rr & (Q - 1)))];
                xr[i][0] = xv.x; xr[i][1] = xv.y; xr[i][2] = xv.z; xr[i][3] = xv.w;
            }
            #pragma unroll
            for (int kk = 0; kk < 4; kk++) {
                int k = h * KHS + k4 * 4 + kk;
                float4 w4 = *(const float4*)&Wl[k * M + cg * 4];
                #pragma unroll
                for (int i = 0; i < RPT; i++) {
                    acc[i].x = fmaf(xr[i][kk], w4.x, acc[i].x);
                    acc[i].y = fmaf(xr[i][kk], w4.y, acc[i].y);
                    acc[i].z = fmaf(xr[i][kk], w4.z, acc[i].z);
                    acc[i].w = fmaf(xr[i][kk], w4.w, acc[i].w);
                }
            }
        }
    }
    float4 bv = {0.f, 0.f, 0.f, 0.f};
    if (EPI == 0) bv = *(const float4*)&b[cg * 4];
    #pragma unroll
    for (int i = 0; i < RPT; i++) {
        int grow = row0 + rt * RPT + i;
        if (grow < nrows) {
            float4 o = acc[i];
            if (EPI == 0) {
                o.x = fmaxf(o.x + bv.x, 0.f);
                o.y = fmaxf(o.y + bv.y, 0.f);
                o.z = fmaxf(o.z + bv.z, 0.f);
                o.w = fmaxf(o.w + bv.w, 0.f);
            } else {
                float dv = dinv[grow];
                o.x *= dv; o.y *= dv; o.z *= dv; o.w *= dv;
            }
            *(float4*)&H[(size_t)grow * M + cg * 4] = o;
        }
    }
}

extern "C" void kernel_launch(void* const* d_in, const int* in_sizes, int n_in,
                              void* d_out, int out_size, void* d_ws, size_t ws_size,
                              hipStream_t stream) {
    const float* x1 = (const float*)d_in[0];
    const int*   e1 = (const int*)d_in[1];
    const float* x2 = (const float*)d_in[2];
    const int*   e2 = (const int*)d_in[3];
    const float* W1 = (const float*)d_in[4];
    const float* b1 = (const float*)d_in[5];
    const float* W2 = (const float*)d_in[6];
    const float* b2 = (const float*)d_in[7];
    float* out = (float*)d_out;

    const int N2 = 2 * N_NODES, E2 = 2 * N_EDGES;
    const int NB = (N2 + 255) / 256;            // 391 scan blocks (<512)

    // Workspace (~83 MB): flag | deg | cursor | dinv | rowptr | partial |
    // blocksum | csr(2E u16) | bufY(2N*64) | bufH(2N*128; first half doubles
    // as sx, consumed by pull-1 before gemm-1 overwrites bufH)
    char* ws = (char*)d_ws;
    int*   flag     = (int*)ws;
    int*   deg      = (int*)(ws + 256);
    int*   cursor   = deg + N2;
    float* dinv     = (float*)(cursor + N2);
    int*   rowptr   = (int*)(dinv + N2);
    int*   partial  = rowptr + (N2 + 1);
    int*   blocksum = partial + N2;             // 512 ints
    unsigned short* csr = (unsigned short*)(blocksum + 512);
    float* bufY     = (float*)(csr + E2);       // 2N*64
    float* bufH     = bufY + (size_t)N2 * 64;   // 2N*128
    float* sx       = bufH;                     // alias: 2N*64 prescaled x

    detect_stride_k<<<1, 1024, 0, stream>>>(e1, flag);

    // ---- CSR build, both graphs ----
    hipMemsetAsync(deg, 0, 2 * (size_t)N2 * sizeof(int), stream);   // deg+cursor
    deg_count_k<<<(E2 + 255) / 256, 256, 0, stream>>>(e1, e2, flag, deg);
    scan1_k<<<NB, 256, 0, stream>>>(deg, dinv, partial, blocksum, N2);
    scan2_k<<<1, 512, 0, stream>>>(blocksum, NB);
    scan3_k<<<NB, 256, 0, stream>>>(partial, blocksum, rowptr, N2, E2);
    scatter_k<<<(E2 + 255) / 256, 256, 0, stream>>>(e1, e2, flag, rowptr, cursor, csr);
    prescale_k<<<(N2 * 16 + 255) / 256, 256, 0, stream>>>(x1, x2, dinv, sx);

    // ---- layer 1: Y = A_hat @ X (on prescaled x), X1 = relu(Y@W1 + b1) ----
    pull_agg_k<false><<<(N2 + 3) / 4, 256, 0, stream>>>(sx, csr, rowptr, dinv, nullptr, bufY, N2);
    gemm_xw_k<64, 128, 32, 8, 1, 0><<<(N2 + 63) / 64, 256, 0, stream>>>(bufY, W1, b1, nullptr, bufH, N2);
    // ---- layer 2: G' = dinv*(X1@W2) (prescaled), out = relu(dinv*(sum+self)+b2) ----
    gemm_xw_k<128, 64, 16, 8, 2, 1><<<(N2 + 127) / 128, 256, 0, stream>>>(bufH, W2, nullptr, dinv, bufY, N2);
    pull_agg_k<true><<<(N2 + 3) / 4, 256, 0, stream>>>(bufY, csr, rowptr, dinv, b2, out, N2);
}

// Round 6
// 340.846 us; speedup vs baseline: 12.6496x; 1.3464x over previous
//
#include <hip/hip_runtime.h>

#define N_NODES 50000
#define N_EDGES 800000
#define NPAD    50176          // 196*256: graph-2 node base, bucket-aligned
#define NBKT    392            // (2*NPAD)/256 buckets of 256 nodes
#define BCAP    6144           // bucket capacity; mean 4082, sigma 64 -> +32 sigma
static_assert(N_NODES < 65536, "u16 CSR requires local node ids < 65536");
// LAYOUT RULE: every intermediate buffer (sx, bufY, bufH) is indexed by the
// PADDED gid (graph g node i -> g*NPAD + i). Compaction to the harness's
// [2*N_NODES, 64] output happens ONLY at the final store in pull-2.

// ---------------------------------------------------------------------------
// Edge-index dtype detection: reference says int64, but JAX (x64 off) demotes
// to int32. If int64 little-endian with values < 2^31, every odd 32-bit word
// is 0. flag = element stride in int32 units (1 or 2).
// ---------------------------------------------------------------------------
__global__ __launch_bounds__(1024) void detect_stride_k(const int* __restrict__ raw,
                                                        int* __restrict__ flag) {
    __shared__ int any_nonzero;
    if (threadIdx.x == 0) any_nonzero = 0;
    __syncthreads();
    int v = raw[2 * threadIdx.x + 1];
    if (v != 0) atomicOr(&any_nonzero, 1);
    __syncthreads();
    if (threadIdx.x == 0) *flag = any_nonzero ? 1 : 2;
}

// ---------------------------------------------------------------------------
// Pass A: bin edges by dst bucket (bucket = gid>>8, gid = g*NPAD + dst).
// Per-block LDS histogram -> one global atomicAdd per (block,bucket) reserves
// a contiguous run in bbuf -> writes are ~84 B runs instead of 2 B random.
// Entry: (dst_in_bucket << 16) | src_local.
// ---------------------------------------------------------------------------
__global__ __launch_bounds__(256) void binA_k(const int* __restrict__ raw1,
        const int* __restrict__ raw2, const int* __restrict__ flag,
        unsigned* __restrict__ bcount, unsigned* __restrict__ bbuf) {
    __shared__ unsigned hist[NBKT], gofs[NBKT];
    const int stride = *flag;
    const int tid = threadIdx.x;
    for (int b = tid; b < NBKT; b += 256) hist[b] = 0u;
    __syncthreads();
    const long long e0 = (long long)blockIdx.x * 8192;
    // loop 1: bucket histogram (dst only)
    #pragma unroll 4
    for (int it = 0; it < 32; it++) {
        long long e = e0 + it * 256 + tid;
        if (e < 2LL * N_EDGES) {
            int g2 = e >= N_EDGES;
            const int* raw = g2 ? raw2 : raw1;
            long long el = e - (g2 ? N_EDGES : 0);
            int d = raw[((long long)N_EDGES + el) * stride];
            atomicAdd(&hist[(g2 * NPAD + d) >> 8], 1u);
        }
    }
    __syncthreads();
    // reserve global runs
    for (int b = tid; b < NBKT; b += 256) {
        unsigned c = hist[b];
        gofs[b] = c ? atomicAdd(&bcount[b], c) : 0u;
    }
    __syncthreads();
    for (int b = tid; b < NBKT; b += 256) hist[b] = 0u;
    __syncthreads();
    // loop 2: place edges
    #pragma unroll 4
    for (int it = 0; it < 32; it++) {
        long long e = e0 + it * 256 + tid;
        if (e < 2LL * N_EDGES) {
            int g2 = e >= N_EDGES;
            const int* raw = g2 ? raw2 : raw1;
            long long el = e - (g2 ? N_EDGES : 0);
            int s = raw[el * stride];
            int d = raw[((long long)N_EDGES + el) * stride];
            int gid = g2 * NPAD + d;
            int bkt = gid >> 8;
            unsigned r = atomicAdd(&hist[bkt], 1u);
            unsigned pos = gofs[bkt] + r;
            if (pos < BCAP)
                bbuf[(size_t)bkt * BCAP + pos] =
                    ((unsigned)(gid & 255) << 16) | (unsigned)s;
        }
    }
}

// Exclusive scan of bucket counts -> per-bucket CSR base.
__global__ __launch_bounds__(512) void bscan_k(const unsigned* __restrict__ bcount,
                                               int* __restrict__ ebase) {
    __shared__ int tmp[512];
    int t = threadIdx.x;
    int v = (t < NBKT) ? (int)bcount[t] : 0;
    tmp[t] = v;
    __syncthreads();
    #pragma unroll
    for (int off = 1; off < 512; off <<= 1) {
        int add = (t >= off) ? tmp[t - off] : 0;
        __syncthreads();
        tmp[t] += add;
        __syncthreads();
    }
    if (t < NBKT) ebase[t] = tmp[t] - v;
}

// ---------------------------------------------------------------------------
// Pass B: one block per bucket. Bucket entries -> LDS; per-node degree
// histogram + LDS scan -> rowptr & dinv; LDS-cursor scatter into the
// bucket's ~8 KB CSR window (single-XCD-local writes, amplification ~1).
// ---------------------------------------------------------------------------
__global__ __launch_bounds__(256) void buildB_k(const unsigned* __restrict__ bcount,
        const int* __restrict__ ebase, const unsigned* __restrict__ bbuf,
        unsigned short* __restrict__ csr, int* __restrict__ rowptr,
        float* __restrict__ dinv) {
    __shared__ unsigned ent[BCAP];
    __shared__ int deg[256], cur[256], tmp[256];
    const int b = blockIdx.x, tid = threadIdx.x;
    const int cnt = min((int)bcount[b], BCAP);
    const int eb = ebase[b];
    for (int i = tid; i < cnt; i += 256) ent[i] = bbuf[(size_t)b * BCAP + i];
    deg[tid] = 0;
    __syncthreads();
    for (int i = tid; i < cnt; i += 256) atomicAdd(&deg[ent[i] >> 16], 1);
    __syncthreads();
    int v = deg[tid];
    tmp[tid] = v;
    __syncthreads();
    #pragma unroll
    for (int off = 1; off < 256; off <<= 1) {
        int add = (tid >= off) ? tmp[tid - off] : 0;
        __syncthreads();
        tmp[tid] += add;
        __syncthreads();
    }
    int excl = tmp[tid] - v;
    cur[tid] = excl;
    int gid = b * 256 + tid;
    rowptr[gid] = eb + excl;
    dinv[gid] = rsqrtf((float)v + 1.0f);            // +1 self-loop
    if (b == NBKT - 1 && tid == 255) rowptr[2 * NPAD] = eb + excl + v;
    __syncthreads();
    for (int i = tid; i < cnt; i += 256) {
        unsigned p = ent[i];
        int pos = atomicAdd(&cur[p >> 16], 1);
        csr[eb + pos] = (unsigned short)(p & 0xFFFFu);
    }
}

// sx[gid] = dinv[gid] * x[gid] in padded layout; pad rows zeroed.
__global__ __launch_bounds__(256) void prescale_k(const float* __restrict__ x1,
        const float* __restrict__ x2, const float* __restrict__ dinv,
        float* __restrict__ sx) {
    int idx = blockIdx.x * 256 + threadIdx.x;        // float4 index
    if (idx >= 2 * NPAD * 16) return;
    int gid = idx >> 4, q = idx & 15;
    int g2 = gid >= NPAD;
    int local = gid - (g2 ? NPAD : 0);
    float4 v = {0.f, 0.f, 0.f, 0.f};
    if (local < N_NODES) {
        const float* x = g2 ? x2 : x1;
        v = *(const float4*)&x[((size_t)local * 16 + q) * 4];
        float dv = dinv[gid];
        v.x *= dv; v.y *= dv; v.z *= dv; v.w *= dv;
    }
    ((float4*)sx)[idx] = v;
}

// ---------------------------------------------------------------------------
// Pull aggregation on PRESCALED features, F=64: one wave per dst node.
// Lane = (sub, fl): 4 edges in parallel, 16 lanes x float4 per edge row.
// out[d] = dinv[d] * (sum_s sh[s] + sh[d]) (+bias, relu).
// COMPACT_OUT: write to the harness's compact [2N,64] layout (final store).
// ---------------------------------------------------------------------------
template<bool BIAS_RELU, bool COMPACT_OUT>
__global__ __launch_bounds__(256) void pull_agg_k(const float* __restrict__ sh,
        const unsigned short* __restrict__ csr, const int* __restrict__ rowptr,
        const float* __restrict__ dinv, const float* __restrict__ bias,
        float* __restrict__ out) {
    const int lane = threadIdx.x & 63;
    const int d = blockIdx.x * 4 + (threadIdx.x >> 6);   // grid exact: d < 2*NPAD
    const int g2 = d >= NPAD;
    const int local = d - (g2 ? NPAD : 0);
    if (local >= N_NODES) return;                         // pad node: never gathered
    const int sub = lane >> 4, fl = lane & 15;
    const int gbase = g2 ? NPAD : 0;
    const int jb = rowptr[d], je = rowptr[d + 1];
    float4 acc = {0.f, 0.f, 0.f, 0.f};
    int j = jb;
    for (; j + 16 <= je; j += 16) {
        int s0 = (int)csr[j      + sub] + gbase;
        int s1 = (int)csr[j + 4  + sub] + gbase;
        int s2 = (int)csr[j + 8  + sub] + gbase;
        int s3 = (int)csr[j + 12 + sub] + gbase;
        float4 v0 = *(const float4*)&sh[(size_t)s0 * 64 + fl * 4];
        float4 v1 = *(const float4*)&sh[(size_t)s1 * 64 + fl * 4];
        float4 v2 = *(const float4*)&sh[(size_t)s2 * 64 + fl * 4];
        float4 v3 = *(const float4*)&sh[(size_t)s3 * 64 + fl * 4];
        acc.x += v0.x + v1.x + v2.x + v3.x;
        acc.y += v0.y + v1.y + v2.y + v3.y;
        acc.z += v0.z + v1.z + v2.z + v3.z;
        acc.w += v0.w + v1.w + v2.w + v3.w;
    }
    for (; j < je; j += 4) {
        int idx = j + sub;
        int ii = (idx < je) ? idx : jb;              // safe addr (row nonempty here)
        int s = (int)csr[ii] + gbase;
        float4 v = *(const float4*)&sh[(size_t)s * 64 + fl * 4];
        if (idx < je) { acc.x += v.x; acc.y += v.y; acc.z += v.z; acc.w += v.w; }
    }
    acc.x += __shfl_xor(acc.x, 16); acc.y += __shfl_xor(acc.y, 16);
    acc.z += __shfl_xor(acc.z, 16); acc.w += __shfl_xor(acc.w, 16);
    acc.x += __shfl_xor(acc.x, 32); acc.y += __shfl_xor(acc.y, 32);
    acc.z += __shfl_xor(acc.z, 32); acc.w += __shfl_xor(acc.w, 32);
    float4 self4 = *(const float4*)&sh[(size_t)d * 64 + fl * 4];
    float dv = dinv[d];
    float4 o;
    o.x = (acc.x + self4.x) * dv;
    o.y = (acc.y + self4.y) * dv;
    o.z = (acc.z + self4.z) * dv;
    o.w = (acc.w + self4.w) * dv;
    if (BIAS_RELU) {
        float4 bv = *(const float4*)&bias[fl * 4];
        o.x = fmaxf(o.x + bv.x, 0.f);
        o.y = fmaxf(o.y + bv.y, 0.f);
        o.z = fmaxf(o.z + bv.z, 0.f);
        o.w = fmaxf(o.w + bv.w, 0.f);
    }
    if (sub == 0) {
        size_t orow = COMPACT_OUT ? (size_t)(g2 ? N_NODES + local : local)
                                  : (size_t)d;       // padded for intermediates
        *(float4*)&out[orow * 64 + fl * 4] = o;
    }
}

// ---------------------------------------------------------------------------
// H = X @ W with fused epilogue on PADDED rows. Per-thread 8 rows x 4 cols;
// X read float4-over-k from XOR-swizzled LDS. EPI: 0 = bias+relu, 1 = row*dinv
// (dinv indexed by the same padded row id as X/H -> consistent by layout rule).
// ---------------------------------------------------------------------------
template<int K, int M, int CG, int RPT, int KH, int EPI>
__global__ __launch_bounds__(256) void gemm_xw_k(const float* __restrict__ X,
        const float* __restrict__ W, const float* __restrict__ b,
        const float* __restrict__ dinv, float* __restrict__ H, int nrows) {
    constexpr int RT  = 256 / CG;
    constexpr int RPB = RT * RPT;
    constexpr int KHS = K / KH;
    constexpr int Q   = KHS / 4;
    __shared__ float Wl[K * M];
    __shared__ float Xl[RPB * KHS];
    const int tid = threadIdx.x;
    const int cg = tid % CG, rt = tid / CG;
    const int row0 = blockIdx.x * RPB;
    for (int i = tid * 4; i < K * M; i += 1024)
        *(float4*)&Wl[i] = *(const float4*)&W[i];
    float4 acc[RPT] = {};
    for (int h = 0; h < KH; h++) {
        __syncthreads();
        for (int i4 = tid; i4 < RPB * Q; i4 += 256) {
            int rr = i4 / Q, q = i4 % Q;
            int grow = row0 + rr;
            float4 v = {0.f, 0.f, 0.f, 0.f};
            if (grow < nrows) v = *(const float4*)&X[(size_t)grow * K + h * KHS + q * 4];
            ((float4*)Xl)[rr * Q + (q ^ (rr & (Q - 1)))] = v;
        }
        __syncthreads();
        for (int k4 = 0; k4 < Q; k4++) {
            float xr[RPT][4];
            #pragma unroll
            for (int i = 0; i < RPT; i++) {
                int rr = rt * RPT + i;
                float4 xv = ((const float4*)Xl)[rr * Q + (k4 ^ (rr & (Q - 1)))];
                xr[i][0] = xv.x; xr[i][1] = xv.y; xr[i][2] = xv.z; xr[i][3] = xv.w;
            }
            #pragma unroll
            for (int kk = 0; kk < 4; kk++) {
                int k = h * KHS + k4 * 4 + kk;
                float4 w4 = *(const float4*)&Wl[k * M + cg * 4];
                #pragma unroll
                for (int i = 0; i < RPT; i++) {
                    acc[i].x = fmaf(xr[i][kk], w4.x, acc[i].x);
                    acc[i].y = fmaf(xr[i][kk], w4.y, acc[i].y);
                    acc[i].z = fmaf(xr[i][kk], w4.z, acc[i].z);
                    acc[i].w = fmaf(xr[i][kk], w4.w, acc[i].w);
                }
            }
        }
    }
    float4 bv = {0.f, 0.f, 0.f, 0.f};
    if (EPI == 0) bv = *(const float4*)&b[cg * 4];
    #pragma unroll
    for (int i = 0; i < RPT; i++) {
        int grow = row0 + rt * RPT + i;
        if (grow < nrows) {
            float4 o = acc[i];
            if (EPI == 0) {
                o.x = fmaxf(o.x + bv.x, 0.f);
                o.y = fmaxf(o.y + bv.y, 0.f);
                o.z = fmaxf(o.z + bv.z, 0.f);
                o.w = fmaxf(o.w + bv.w, 0.f);
            } else {
                float dv = dinv[grow];
                o.x *= dv; o.y *= dv; o.z *= dv; o.w *= dv;
            }
            *(float4*)&H[(size_t)grow * M + cg * 4] = o;
        }
    }
}

extern "C" void kernel_launch(void* const* d_in, const int* in_sizes, int n_in,
                              void* d_out, int out_size, void* d_ws, size_t ws_size,
                              hipStream_t stream) {
    const float* x1 = (const float*)d_in[0];
    const int*   e1 = (const int*)d_in[1];
    const float* x2 = (const float*)d_in[2];
    const int*   e2 = (const int*)d_in[3];
    const float* W1 = (const float*)d_in[4];
    const float* b1 = (const float*)d_in[5];
    const float* W2 = (const float*)d_in[6];
    const float* b2 = (const float*)d_in[7];
    float* out = (float*)d_out;

    // Workspace (~92 MB), 256 B-aligned chunks.
    char* p = (char*)d_ws;
    auto alloc = [&](size_t bytes) { char* r = p; p += (bytes + 255) & ~(size_t)255; return r; };
    int*      flag   = (int*)alloc(4);
    unsigned* bcount = (unsigned*)alloc(NBKT * 4);
    int*      ebase  = (int*)alloc(NBKT * 4);
    float*    dinv   = (float*)alloc((size_t)2 * NPAD * 4);
    int*      rowptr = (int*)alloc(((size_t)2 * NPAD + 1) * 4);
    unsigned* bbuf   = (unsigned*)alloc((size_t)NBKT * BCAP * 4);
    unsigned short* csr = (unsigned short*)alloc((size_t)2 * N_EDGES * 2);
    float*    bufY   = (float*)alloc((size_t)2 * NPAD * 64 * 4);
    float*    bufH   = (float*)alloc((size_t)2 * NPAD * 128 * 4);
    float*    sx     = bufH;   // alias: consumed by pull-1 before gemm-1 writes bufH

    detect_stride_k<<<1, 1024, 0, stream>>>(e1, flag);

    // ---- bucketed CSR build (replaces deg_count + 3 scans + scatter) ----
    hipMemsetAsync(bcount, 0, NBKT * 4, stream);
    binA_k<<<196, 256, 0, stream>>>(e1, e2, flag, bcount, bbuf);
    bscan_k<<<1, 512, 0, stream>>>(bcount, ebase);
    buildB_k<<<NBKT, 256, 0, stream>>>(bcount, ebase, bbuf, csr, rowptr, dinv);

    prescale_k<<<(2 * NPAD * 16) / 256, 256, 0, stream>>>(x1, x2, dinv, sx);

    // ---- layer 1: Y = A_hat @ X (prescaled), X1 = relu(Y@W1 + b1) ----
    pull_agg_k<false, false><<<2 * NPAD / 4, 256, 0, stream>>>(sx, csr, rowptr, dinv, nullptr, bufY);
    gemm_xw_k<64, 128, 32, 8, 1, 0><<<2 * NPAD / 64, 256, 0, stream>>>(bufY, W1, b1, nullptr, bufH, 2 * NPAD);
    // ---- layer 2: G' = dinv*(X1@W2), out = relu(dinv*(sum+self)+b2) ----
    gemm_xw_k<128, 64, 16, 8, 2, 1><<<2 * NPAD / 128, 256, 0, stream>>>(bufH, W2, nullptr, dinv, bufY, 2 * NPAD);
    pull_agg_k<true, true><<<2 * NPAD / 4, 256, 0, stream>>>(bufY, csr, rowptr, dinv, b2, out);
}

// Round 7
// 322.425 us; speedup vs baseline: 13.3723x; 1.0571x over previous
//
#include <hip/hip_runtime.h>
#include <hip/hip_fp16.h>

#define N_NODES 50000
#define N_EDGES 800000
#define NPAD    50176          // 196*256: graph-2 node base, bucket-aligned
#define NBKT    392            // (2*NPAD)/256 buckets of 256 nodes
#define BCAP    6144           // bucket capacity; mean 4082, sigma 64 -> +32 sigma
static_assert(N_NODES < 65536, "u16 CSR requires local node ids < 65536");
// LAYOUT RULE: every intermediate buffer is indexed by the PADDED gid
// (graph g node i -> g*NPAD + i). Compaction to the harness's [2*N_NODES,64]
// output happens ONLY at the final store in pull-2.
// Gather-side feature buffers (sxh, gh) are fp16 (128 B/row = 1 cache line);
// accumulation stays fp32.

// Per-block edge-index stride detection (int64 vs int32, see R0 note):
// odd 32-bit words of an int64 little-endian buffer with values < 2^31 are 0.
__device__ __forceinline__ int detect_stride_block(const int* raw1, int* sflag) {
    int odd = 0;
    for (int i = threadIdx.x; i < 2048; i += 256) odd |= raw1[2 * i + 1];
    if (threadIdx.x == 0) *sflag = 0;
    __syncthreads();
    if (odd) atomicOr(sflag, 1);
    __syncthreads();
    return *sflag ? 1 : 2;
}

// ---------------------------------------------------------------------------
// Pass A: bin edges by dst bucket (bucket = gid>>8, gid = g*NPAD + dst).
// Per-block LDS histogram -> one global atomicAdd per (block,bucket) reserves
// a contiguous run in bbuf. Entry: (dst_in_bucket << 16) | src_local.
// ---------------------------------------------------------------------------
__global__ __launch_bounds__(256) void binA_k(const int* __restrict__ raw1,
        const int* __restrict__ raw2, unsigned* __restrict__ bcount,
        unsigned* __restrict__ bbuf) {
    __shared__ unsigned hist[NBKT], gofs[NBKT];
    __shared__ int sflag;
    const int stride = detect_stride_block(raw1, &sflag);
    const int tid = threadIdx.x;
    for (int b = tid; b < NBKT; b += 256) hist[b] = 0u;
    __syncthreads();
    const long long e0 = (long long)blockIdx.x * 8192;
    #pragma unroll 4
    for (int it = 0; it < 32; it++) {
        long long e = e0 + it * 256 + tid;
        if (e < 2LL * N_EDGES) {
            int g2 = e >= N_EDGES;
            const int* raw = g2 ? raw2 : raw1;
            long long el = e - (g2 ? N_EDGES : 0);
            int d = raw[((long long)N_EDGES + el) * stride];
            atomicAdd(&hist[(g2 * NPAD + d) >> 8], 1u);
        }
    }
    __syncthreads();
    for (int b = tid; b < NBKT; b += 256) {
        unsigned c = hist[b];
        gofs[b] = c ? atomicAdd(&bcount[b], c) : 0u;
    }
    __syncthreads();
    for (int b = tid; b < NBKT; b += 256) hist[b] = 0u;
    __syncthreads();
    #pragma unroll 4
    for (int it = 0; it < 32; it++) {
        long long e = e0 + it * 256 + tid;
        if (e < 2LL * N_EDGES) {
            int g2 = e >= N_EDGES;
            const int* raw = g2 ? raw2 : raw1;
            long long el = e - (g2 ? N_EDGES : 0);
            int s = raw[el * stride];
            int d = raw[((long long)N_EDGES + el) * stride];
            int gid = g2 * NPAD + d;
            int bkt = gid >> 8;
            unsigned r = atomicAdd(&hist[bkt], 1u);
            unsigned pos = gofs[bkt] + r;
            if (pos < BCAP)
                bbuf[(size_t)bkt * BCAP + pos] =
                    ((unsigned)(gid & 255) << 16) | (unsigned)s;
        }
    }
}

// ---------------------------------------------------------------------------
// Pass B: one block per bucket. Folds in: bucket-count scan (per-block, LDS),
// per-node degree + rowptr + dinv, LDS-cursor CSR scatter, and the fp16
// prescale sxh[gid] = half(dinv[gid] * x[gid]) for this bucket's 256 nodes.
// ---------------------------------------------------------------------------
__global__ __launch_bounds__(256) void buildB_k(const unsigned* __restrict__ bcount,
        const unsigned* __restrict__ bbuf, const float* __restrict__ x1,
        const float* __restrict__ x2, unsigned short* __restrict__ csr,
        int* __restrict__ rowptr, float* __restrict__ dinv,
        __half* __restrict__ sxh) {
    __shared__ unsigned ent[BCAP];
    __shared__ int deg[256], cur[256], tmp[256], tmp2[512];
    __shared__ float sdinv[256];
    const int b = blockIdx.x, tid = threadIdx.x;
    // per-block exclusive scan of all bucket counts -> this bucket's CSR base
    {
        int v = (tid < NBKT) ? (int)bcount[tid] : 0;
        tmp2[tid] = v; tmp2[tid + 256] = (tid + 256 < NBKT) ? (int)bcount[tid + 256] : 0;
        __syncthreads();
        #pragma unroll
        for (int off = 1; off < 512; off <<= 1) {
            int a0 = (tid >= off) ? tmp2[tid - off] : 0;
            int a1 = (tid + 256 >= off) ? tmp2[tid + 256 - off] : 0;
            __syncthreads();
            tmp2[tid] += a0; tmp2[tid + 256] += a1;
            __syncthreads();
        }
    }
    const int cnt = min((int)bcount[b], BCAP);
    const int eb = tmp2[b] - (int)bcount[b];     // exclusive prefix
    for (int i = tid; i < cnt; i += 256) ent[i] = bbuf[(size_t)b * BCAP + i];
    deg[tid] = 0;
    __syncthreads();
    for (int i = tid; i < cnt; i += 256) atomicAdd(&deg[ent[i] >> 16], 1);
    __syncthreads();
    int v = deg[tid];
    tmp[tid] = v;
    __syncthreads();
    #pragma unroll
    for (int off = 1; off < 256; off <<= 1) {
        int add = (tid >= off) ? tmp[tid - off] : 0;
        __syncthreads();
        tmp[tid] += add;
        __syncthreads();
    }
    int excl = tmp[tid] - v;
    cur[tid] = excl;
    const int gid = b * 256 + tid;
    float dv = rsqrtf((float)v + 1.0f);          // +1 self-loop
    rowptr[gid] = eb + excl;
    dinv[gid] = dv;
    sdinv[tid] = dv;
    if (b == NBKT - 1 && tid == 255) rowptr[2 * NPAD] = eb + excl + v;
    __syncthreads();
    for (int i = tid; i < cnt; i += 256) {
        unsigned p = ent[i];
        int pos = atomicAdd(&cur[p >> 16], 1);
        csr[eb + pos] = (unsigned short)(p & 0xFFFFu);
    }
    // fused fp16 prescale for this bucket's nodes
    const int g2 = (b * 256) >= NPAD;            // buckets never straddle graphs
    const float* x = g2 ? x2 : x1;
    const int lbase = b * 256 - (g2 ? NPAD : 0);
    for (int i = tid; i < 256 * 16; i += 256) {  // (node, float4-chunk)
        int n = i >> 4, q = i & 15;
        int local = lbase + n;
        __half2 lo = __floats2half2_rn(0.f, 0.f), hi = lo;
        if (local < N_NODES) {
            float4 vx = *(const float4*)&x[((size_t)local * 16 + q) * 4];
            float dn = sdinv[n];
            lo = __floats2half2_rn(vx.x * dn, vx.y * dn);
            hi = __floats2half2_rn(vx.z * dn, vx.w * dn);
        }
        uint2 u; u.x = *(unsigned*)&lo; u.y = *(unsigned*)&hi;
        *(uint2*)&sxh[(size_t)(b * 256 + n) * 64 + q * 4] = u;
    }
}

// ---------------------------------------------------------------------------
// Pull aggregation on PRESCALED fp16 features: one wave per dst node.
// Lane = (sub, fl): 4 edges in parallel, 16 lanes x 4 halfs (uint2) per edge.
// out[d] = dinv[d] * (sum_s sh[s] + sh[d]) (+bias, relu). fp32 accumulate.
// ---------------------------------------------------------------------------
__device__ __forceinline__ void acc_h4(float4& acc, uint2 u) {
    float2 f0 = __half22float2(*(__half2*)&u.x);
    float2 f1 = __half22float2(*(__half2*)&u.y);
    acc.x += f0.x; acc.y += f0.y; acc.z += f1.x; acc.w += f1.y;
}

template<bool BIAS_RELU, bool COMPACT_OUT>
__global__ __launch_bounds__(256) void pull_agg_k(const __half* __restrict__ sh,
        const unsigned short* __restrict__ csr, const int* __restrict__ rowptr,
        const float* __restrict__ dinv, const float* __restrict__ bias,
        float* __restrict__ out) {
    const int lane = threadIdx.x & 63;
    const int d = blockIdx.x * 4 + (threadIdx.x >> 6);   // grid exact: d < 2*NPAD
    const int g2 = d >= NPAD;
    const int local = d - (g2 ? NPAD : 0);
    if (local >= N_NODES) return;                         // pad node: never gathered
    const int sub = lane >> 4, fl = lane & 15;
    const int gbase = g2 ? NPAD : 0;
    const int jb = rowptr[d], je = rowptr[d + 1];
    float4 acc = {0.f, 0.f, 0.f, 0.f};
    int j = jb;
    for (; j + 16 <= je; j += 16) {
        int s0 = (int)csr[j      + sub] + gbase;
        int s1 = (int)csr[j + 4  + sub] + gbase;
        int s2 = (int)csr[j + 8  + sub] + gbase;
        int s3 = (int)csr[j + 12 + sub] + gbase;
        uint2 u0 = *(const uint2*)&sh[(size_t)s0 * 64 + fl * 4];
        uint2 u1 = *(const uint2*)&sh[(size_t)s1 * 64 + fl * 4];
        uint2 u2 = *(const uint2*)&sh[(size_t)s2 * 64 + fl * 4];
        uint2 u3 = *(const uint2*)&sh[(size_t)s3 * 64 + fl * 4];
        acc_h4(acc, u0); acc_h4(acc, u1); acc_h4(acc, u2); acc_h4(acc, u3);
    }
    for (; j < je; j += 4) {
        int idx = j + sub;
        int ii = (idx < je) ? idx : jb;              // safe addr (row nonempty here)
        int s = (int)csr[ii] + gbase;
        uint2 u = *(const uint2*)&sh[(size_t)s * 64 + fl * 4];
        if (idx < je) acc_h4(acc, u);
    }
    acc.x += __shfl_xor(acc.x, 16); acc.y += __shfl_xor(acc.y, 16);
    acc.z += __shfl_xor(acc.z, 16); acc.w += __shfl_xor(acc.w, 16);
    acc.x += __shfl_xor(acc.x, 32); acc.y += __shfl_xor(acc.y, 32);
    acc.z += __shfl_xor(acc.z, 32); acc.w += __shfl_xor(acc.w, 32);
    uint2 su = *(const uint2*)&sh[(size_t)d * 64 + fl * 4];
    float4 self;
    { float2 f0 = __half22float2(*(__half2*)&su.x), f1 = __half22float2(*(__half2*)&su.y);
      self.x = f0.x; self.y = f0.y; self.z = f1.x; self.w = f1.y; }
    float dv = dinv[d];
    float4 o;
    o.x = (acc.x + self.x) * dv;
    o.y = (acc.y + self.y) * dv;
    o.z = (acc.z + self.z) * dv;
    o.w = (acc.w + self.w) * dv;
    if (BIAS_RELU) {
        float4 bv = *(const float4*)&bias[fl * 4];
        o.x = fmaxf(o.x + bv.x, 0.f);
        o.y = fmaxf(o.y + bv.y, 0.f);
        o.z = fmaxf(o.z + bv.z, 0.f);
        o.w = fmaxf(o.w + bv.w, 0.f);
    }
    if (sub == 0) {
        size_t orow = COMPACT_OUT ? (size_t)(g2 ? N_NODES + local : local)
                                  : (size_t)d;       // padded for intermediates
        *(float4*)&out[orow * 64 + fl * 4] = o;
    }
}

// ---------------------------------------------------------------------------
// H = X @ W with fused epilogue on PADDED rows. Per-thread 8 rows x 4 cols;
// X read float4-over-k from XOR-swizzled LDS.
// EPI 0: H(fp32) = relu(acc + b).  EPI 1: Hh(fp16) = dinv[row] * acc.
// ---------------------------------------------------------------------------
template<int K, int M, int CG, int RPT, int KH, int EPI>
__global__ __launch_bounds__(256) void gemm_xw_k(const float* __restrict__ X,
        const float* __restrict__ W, const float* __restrict__ b,
        const float* __restrict__ dinv, float* __restrict__ H,
        __half* __restrict__ Hh, int nrows) {
    constexpr int RT  = 256 / CG;
    constexpr int RPB = RT * RPT;
    constexpr int KHS = K / KH;
    constexpr int Q   = KHS / 4;
    __shared__ float Wl[K * M];
    __shared__ float Xl[RPB * KHS];
    const int tid = threadIdx.x;
    const int cg = tid % CG, rt = tid / CG;
    const int row0 = blockIdx.x * RPB;
    for (int i = tid * 4; i < K * M; i += 1024)
        *(float4*)&Wl[i] = *(const float4*)&W[i];
    float4 acc[RPT] = {};
    for (int h = 0; h < KH; h++) {
        __syncthreads();
        for (int i4 = tid; i4 < RPB * Q; i4 += 256) {
            int rr = i4 / Q, q = i4 % Q;
            int grow = row0 + rr;
            float4 v = {0.f, 0.f, 0.f, 0.f};
            if (grow < nrows) v = *(const float4*)&X[(size_t)grow * K + h * KHS + q * 4];
            ((float4*)Xl)[rr * Q + (q ^ (rr & (Q - 1)))] = v;
        }
        __syncthreads();
        for (int k4 = 0; k4 < Q; k4++) {
            float xr[RPT][4];
            #pragma unroll
            for (int i = 0; i < RPT; i++) {
                int rr = rt * RPT + i;
                float4 xv = ((const float4*)Xl)[rr * Q + (k4 ^ (rr & (Q - 1)))];
                xr[i][0] = xv.x; xr[i][1] = xv.y; xr[i][2] = xv.z; xr[i][3] = xv.w;
            }
            #pragma unroll
            for (int kk = 0; kk < 4; kk++) {
                int k = h * KHS + k4 * 4 + kk;
                float4 w4 = *(const float4*)&Wl[k * M + cg * 4];
                #pragma unroll
                for (int i = 0; i < RPT; i++) {
                    acc[i].x = fmaf(xr[i][kk], w4.x, acc[i].x);
                    acc[i].y = fmaf(xr[i][kk], w4.y, acc[i].y);
                    acc[i].z = fmaf(xr[i][kk], w4.z, acc[i].z);
                    acc[i].w = fmaf(xr[i][kk], w4.w, acc[i].w);
                }
            }
        }
    }
    float4 bv = {0.f, 0.f, 0.f, 0.f};
    if (EPI == 0) bv = *(const float4*)&b[cg * 4];
    #pragma unroll
    for (int i = 0; i < RPT; i++) {
        int grow = row0 + rt * RPT + i;
        if (grow < nrows) {
            float4 o = acc[i];
            if (EPI == 0) {
                o.x = fmaxf(o.x + bv.x, 0.f);
                o.y = fmaxf(o.y + bv.y, 0.f);
                o.z = fmaxf(o.z + bv.z, 0.f);
                o.w = fmaxf(o.w + bv.w, 0.f);
                *(float4*)&H[(size_t)grow * M + cg * 4] = o;
            } else {
                float dv = dinv[grow];
                __half2 lo = __floats2half2_rn(o.x * dv, o.y * dv);
                __half2 hi = __floats2half2_rn(o.z * dv, o.w * dv);
                uint2 u; u.x = *(unsigned*)&lo; u.y = *(unsigned*)&hi;
                *(uint2*)&Hh[(size_t)grow * M + cg * 4] = u;
            }
        }
    }
}

extern "C" void kernel_launch(void* const* d_in, const int* in_sizes, int n_in,
                              void* d_out, int out_size, void* d_ws, size_t ws_size,
                              hipStream_t stream) {
    const float* x1 = (const float*)d_in[0];
    const int*   e1 = (const int*)d_in[1];
    const float* x2 = (const float*)d_in[2];
    const int*   e2 = (const int*)d_in[3];
    const float* W1 = (const float*)d_in[4];
    const float* b1 = (const float*)d_in[5];
    const float* W2 = (const float*)d_in[6];
    const float* b2 = (const float*)d_in[7];
    float* out = (float*)d_out;

    // Workspace (~80 MB), 256 B-aligned chunks.
    char* p = (char*)d_ws;
    auto alloc = [&](size_t bytes) { char* r = p; p += (bytes + 255) & ~(size_t)255; return r; };
    unsigned* bcount = (unsigned*)alloc(NBKT * 4);
    float*    dinv   = (float*)alloc((size_t)2 * NPAD * 4);
    int*      rowptr = (int*)alloc(((size_t)2 * NPAD + 1) * 4);
    unsigned* bbuf   = (unsigned*)alloc((size_t)NBKT * BCAP * 4);
    unsigned short* csr = (unsigned short*)alloc((size_t)2 * N_EDGES * 2);
    __half*   sxh    = (__half*)alloc((size_t)2 * NPAD * 64 * 2);   // fp16 gather feats
    float*    bufY   = (float*)alloc((size_t)2 * NPAD * 64 * 4);
    float*    bufH   = (float*)alloc((size_t)2 * NPAD * 128 * 4);
    __half*   gh     = sxh;    // alias: sxh consumed by pull-1 before gemm-2 writes

    // ---- CSR build + dinv + fp16 prescale (3 kernels) ----
    hipMemsetAsync(bcount, 0, NBKT * 4, stream);
    binA_k<<<196, 256, 0, stream>>>(e1, e2, bcount, bbuf);
    buildB_k<<<NBKT, 256, 0, stream>>>(bcount, bbuf, x1, x2, csr, rowptr, dinv, sxh);

    // ---- layer 1: Y = A_hat @ X (prescaled fp16), X1 = relu(Y@W1 + b1) ----
    pull_agg_k<false, false><<<2 * NPAD / 4, 256, 0, stream>>>(sxh, csr, rowptr, dinv, nullptr, bufY);
    gemm_xw_k<64, 128, 32, 8, 1, 0><<<2 * NPAD / 64, 256, 0, stream>>>(bufY, W1, b1, nullptr, bufH, nullptr, 2 * NPAD);
    // ---- layer 2: G' = fp16(dinv*(X1@W2)), out = relu(dinv*(sum+self)+b2) ----
    gemm_xw_k<128, 64, 16, 8, 2, 1><<<2 * NPAD / 128, 256, 0, stream>>>(bufH, W2, nullptr, dinv, nullptr, gh, 2 * NPAD);
    pull_agg_k<true, true><<<2 * NPAD / 4, 256, 0, stream>>>(gh, csr, rowptr, dinv, b2, out);
}